// Round 5
// baseline (480.724 us; speedup 1.0000x reference)
//
#include <hip/hip_runtime.h>
#include <math.h>

#define NN 65536
#define NE 1048576
#define DEG_SCALE 33554432.0f  // 2^25

__device__ inline float4 f4fma(float s, float4 v, float4 a) {
    a.x = fmaf(s, v.x, a.x);
    a.y = fmaf(s, v.y, a.y);
    a.z = fmaf(s, v.z, a.z);
    a.w = fmaf(s, v.w, a.w);
    return a;
}

// ---------------- setup kernels ----------------

// one 64-bit atomic per edge: high32 = count, low32 = fixed-point(ew * 2^25).
// weighted degree < 64 -> low word < 2^31, never carries into count.
// atomic returns old value -> old count == this edge's rank within its target bin.
__global__ void __launch_bounds__(256) deg_count(const int* __restrict__ col,
                                                 const float* __restrict__ ew,
                                                 unsigned long long* __restrict__ cntdeg,
                                                 int* __restrict__ rank) {
    int e = blockIdx.x * 256 + threadIdx.x;
    if (e < NE) {
        int c = col[e];
        unsigned long long p = (1ull << 32) | (unsigned long long)__float2uint_rn(ew[e] * DEG_SCALE);
        unsigned long long old = atomicAdd(&cntdeg[c], p);
        rank[e] = (int)(old >> 32);
    }
}

// exclusive scan of counts (high words of cntdeg) -> row_ptr[NN+1]; also emits dinv.
__global__ void __launch_bounds__(1024) scan_kernel(const unsigned long long* __restrict__ cntdeg,
                                                    int* __restrict__ row_ptr,
                                                    float* __restrict__ dinv) {
    __shared__ int ls[1024];
    const int t = threadIdx.x;
    const int CH = NN / 1024;  // 64
    const int base = t * CH;
    int s = 0;
#pragma unroll
    for (int i = 0; i < CH; ++i) {
        unsigned long long v = cntdeg[base + i];
        s += (int)(v >> 32);
        float deg = (float)(unsigned)(v & 0xffffffffull) * (1.0f / DEG_SCALE) + 1.0f;
        dinv[base + i] = 1.0f / sqrtf(deg);  // deg >= 1 (self-loop)
    }
    ls[t] = s;
    __syncthreads();
    for (int off = 1; off < 1024; off <<= 1) {
        int v = (t >= off) ? ls[t - off] : 0;
        __syncthreads();
        ls[t] += v;
        __syncthreads();
    }
    int run = (t == 0) ? 0 : ls[t - 1];
    for (int i = 0; i < CH; ++i) { row_ptr[base + i] = run; run += (int)(cntdeg[base + i] >> 32); }
    if (t == 1023) row_ptr[NN] = run;
}

// atomic-free CSR fill using precomputed rank.
__global__ void __launch_bounds__(256) fill_kernel(const int* __restrict__ row,
                                                   const int* __restrict__ col,
                                                   const float* __restrict__ ew,
                                                   const float* __restrict__ dinv,
                                                   const int* __restrict__ row_ptr,
                                                   const int* __restrict__ rank,
                                                   int2* __restrict__ epack) {
    int e = blockIdx.x * 256 + threadIdx.x;
    if (e < NE) {
        int c = col[e], r = row[e];
        int idx = row_ptr[c] + rank[e];
        int2 p;
        p.x = r;
        p.y = __float_as_int(dinv[r] * ew[e] * dinv[c]);
        epack[idx] = p;
    }
}

// ---------------- per-layer kernels ----------------

// C[NN x 64] = A[NN x K] @ W[K x 64]; 64-node x 64-col tile per block, 4x4 per thread.
template <int K>
__global__ void __launch_bounds__(256) mm64t(const float* __restrict__ A,
                                             const float* __restrict__ W,
                                             float* __restrict__ C) {
    __shared__ float As[64 * 68];
    __shared__ float Ws[64 * 64];
    const int tid = threadIdx.x;
    const int tx = tid & 15;
    const int ty = tid >> 4;
    const int node0 = blockIdx.x * 64;
    float4 acc[4];
#pragma unroll
    for (int m = 0; m < 4; ++m) acc[m] = make_float4(0.f, 0.f, 0.f, 0.f);

    for (int kc = 0; kc < K; kc += 64) {
#pragma unroll
        for (int p = 0; p < 4; ++p) {
            int idx = tid + p * 256;
            int r = idx >> 4, c4 = idx & 15;
            float4 v = *reinterpret_cast<const float4*>(A + (size_t)(node0 + r) * K + kc + c4 * 4);
            *reinterpret_cast<float4*>(&As[r * 68 + c4 * 4]) = v;
        }
#pragma unroll
        for (int p = 0; p < 4; ++p) {
            int idx = tid + p * 256;
            int r = idx >> 4, c4 = idx & 15;
            float4 v = *reinterpret_cast<const float4*>(W + (size_t)(kc + r) * 64 + c4 * 4);
            *reinterpret_cast<float4*>(&Ws[r * 64 + c4 * 4]) = v;
        }
        __syncthreads();
#pragma unroll 16
        for (int k = 0; k < 64; ++k) {
            float4 w = *reinterpret_cast<const float4*>(&Ws[k * 64 + tx * 4]);
            float a0 = As[(ty * 4 + 0) * 68 + k];
            float a1 = As[(ty * 4 + 1) * 68 + k];
            float a2 = As[(ty * 4 + 2) * 68 + k];
            float a3 = As[(ty * 4 + 3) * 68 + k];
            acc[0] = f4fma(a0, w, acc[0]);
            acc[1] = f4fma(a1, w, acc[1]);
            acc[2] = f4fma(a2, w, acc[2]);
            acc[3] = f4fma(a3, w, acc[3]);
        }
        __syncthreads();
    }
#pragma unroll
    for (int m = 0; m < 4; ++m)
        *reinterpret_cast<float4*>(C + (size_t)(node0 + ty * 4 + m) * 64 + tx * 4) = acc[m];
}

// out[n][:] = act( b + dinv[n]^2*T[n] + sum_e enorm[e]*T[esrc[e]] )
// wave per node; 4 edge-groups x 16 lanes (float4/lane), 4x unrolled -> 16 row loads in flight.
// epack stream loaded non-temporally to keep T resident in L2.
template <bool RELU>
__global__ void __launch_bounds__(256) gather64(const float* __restrict__ T,
                                                const float* __restrict__ bias,
                                                const float* __restrict__ dinv,
                                                const int* __restrict__ row_ptr,
                                                const long long* __restrict__ epack,
                                                float* __restrict__ out) {
    const int tid = threadIdx.x;
    const int lane = tid & 63;
    const int g = lane >> 4;   // edge group 0..3
    const int l = lane & 15;   // float4 index within row
    const int node = blockIdx.x * 4 + (tid >> 6);
    const float4* T4 = reinterpret_cast<const float4*>(T);

    const float dv = dinv[node];
    float4 acc = make_float4(0.f, 0.f, 0.f, 0.f);
    if (g == 0) {
        float4 b4 = reinterpret_cast<const float4*>(bias)[l];
        float4 ts = T4[(size_t)node * 16 + l];
        acc.x = b4.x + dv * dv * ts.x;
        acc.y = b4.y + dv * dv * ts.y;
        acc.z = b4.z + dv * dv * ts.z;
        acc.w = b4.w + dv * dv * ts.w;
    }
    const int s = row_ptr[node];
    const int e = row_ptr[node + 1];
    int i = s + g;
    for (; i + 12 < e; i += 16) {
        long long p0 = __builtin_nontemporal_load(&epack[i]);
        long long p1 = __builtin_nontemporal_load(&epack[i + 4]);
        long long p2 = __builtin_nontemporal_load(&epack[i + 8]);
        long long p3 = __builtin_nontemporal_load(&epack[i + 12]);
        float4 r0 = T4[(size_t)(int)p0 * 16 + l];
        float4 r1 = T4[(size_t)(int)p1 * 16 + l];
        float4 r2 = T4[(size_t)(int)p2 * 16 + l];
        float4 r3 = T4[(size_t)(int)p3 * 16 + l];
        acc = f4fma(__int_as_float((int)(p0 >> 32)), r0, acc);
        acc = f4fma(__int_as_float((int)(p1 >> 32)), r1, acc);
        acc = f4fma(__int_as_float((int)(p2 >> 32)), r2, acc);
        acc = f4fma(__int_as_float((int)(p3 >> 32)), r3, acc);
    }
    for (; i < e; i += 4) {
        long long p0 = __builtin_nontemporal_load(&epack[i]);
        acc = f4fma(__int_as_float((int)(p0 >> 32)), T4[(size_t)(int)p0 * 16 + l], acc);
    }
    // reduce across the 4 edge groups (butterfly over lane bits 4,5)
    acc.x += __shfl_xor(acc.x, 16);
    acc.y += __shfl_xor(acc.y, 16);
    acc.z += __shfl_xor(acc.z, 16);
    acc.w += __shfl_xor(acc.w, 16);
    acc.x += __shfl_xor(acc.x, 32);
    acc.y += __shfl_xor(acc.y, 32);
    acc.z += __shfl_xor(acc.z, 32);
    acc.w += __shfl_xor(acc.w, 32);
    if (RELU) {
        acc.x = fmaxf(acc.x, 0.f);
        acc.y = fmaxf(acc.y, 0.f);
        acc.z = fmaxf(acc.z, 0.f);
        acc.w = fmaxf(acc.w, 0.f);
    }
    if (g == 0) reinterpret_cast<float4*>(out)[(size_t)node * 16 + l] = acc;
}

// T8[NN x 2] = A[NN x 64] @ W8[64 x 2]; wave per node, shuffle reduction.
__global__ void __launch_bounds__(256) mm2(const float* __restrict__ A,
                                           const float* __restrict__ W8,
                                           float* __restrict__ T8) {
    const int lane = threadIdx.x & 63;
    const int node = blockIdx.x * 4 + (threadIdx.x >> 6);
    const float a = A[(size_t)node * 64 + lane];
    float p0 = a * W8[lane * 2 + 0];
    float p1 = a * W8[lane * 2 + 1];
    for (int o = 32; o > 0; o >>= 1) {
        p0 += __shfl_xor(p0, o);
        p1 += __shfl_xor(p1, o);
    }
    if (lane == 0) {
        T8[node * 2 + 0] = p0;
        T8[node * 2 + 1] = p1;
    }
}

// wave per node; lane = (edge j 0..31) x (col c 0..1); 32 edges in flight.
__global__ void __launch_bounds__(256) gather2(const float* __restrict__ T8,
                                               const float* __restrict__ b8,
                                               const float* __restrict__ dinv,
                                               const int* __restrict__ row_ptr,
                                               const int2* __restrict__ epack,
                                               float* __restrict__ out) {
    const int lane = threadIdx.x & 63;
    const int c = lane & 1;
    const int j = lane >> 1;  // 0..31
    const int node = blockIdx.x * 4 + (threadIdx.x >> 6);
    const int s = row_ptr[node];
    const int e = row_ptr[node + 1];
    float acc = 0.f;
    for (int i = s + j; i < e; i += 32) {
        int2 p = epack[i];
        acc += __int_as_float(p.y) * T8[(size_t)p.x * 2 + c];
    }
    acc += __shfl_xor(acc, 2);
    acc += __shfl_xor(acc, 4);
    acc += __shfl_xor(acc, 8);
    acc += __shfl_xor(acc, 16);
    acc += __shfl_xor(acc, 32);
    if (j == 0) {
        const float dv = dinv[node];
        out[(size_t)node * 2 + c] = b8[c] + dv * dv * T8[(size_t)node * 2 + c] + acc;
    }
}

// ---------------- launcher ----------------

extern "C" void kernel_launch(void* const* d_in, const int* in_sizes, int n_in,
                              void* d_out, int out_size, void* d_ws, size_t ws_size,
                              hipStream_t stream) {
    const float* x  = (const float*)d_in[0];
    const int*   ei = (const int*)d_in[1];   // [2, NE]: [0:NE)=row(src), [NE:2NE)=col(dst)
    const float* ea = (const float*)d_in[2];
    const float* W1 = (const float*)d_in[3];
    const float* b1 = (const float*)d_in[4];
    const float* W2 = (const float*)d_in[5];
    const float* b2 = (const float*)d_in[6];
    const float* W3 = (const float*)d_in[7];
    const float* b3 = (const float*)d_in[8];
    const float* W4 = (const float*)d_in[9];
    const float* b4 = (const float*)d_in[10];
    const float* W5 = (const float*)d_in[11];
    const float* b5 = (const float*)d_in[12];
    const float* W8 = (const float*)d_in[13];
    const float* b8 = (const float*)d_in[14];
    float* out = (float*)d_out;

    // workspace layout (fp32/i32 words)
    float* T      = (float*)d_ws;                 // NN*64
    float* A      = T + (size_t)NN * 64;          // NN*64  (rank aliases A: rank is dead
    int*   rank   = (int*)A;                      //         before gather64 first writes A)
    int2*  epack  = (int2*)(A + (size_t)NN * 64); // NE int2
    unsigned long long* cntdeg = (unsigned long long*)(epack + NE);  // NN ull
    float* dinv   = (float*)(cntdeg + NN);        // NN
    int*   row_ptr= (int*)(dinv + NN);            // NN+1
    float* T8     = (float*)(row_ptr + NN + 1);   // NN*2

    const int* e_row = ei;
    const int* e_col = ei + NE;

    (void)hipMemsetAsync(cntdeg, 0, (size_t)NN * 8, stream);  // cntdeg only

    deg_count<<<NE / 256, 256, 0, stream>>>(e_col, ea, cntdeg, rank);
    scan_kernel<<<1, 1024, 0, stream>>>(cntdeg, row_ptr, dinv);
    fill_kernel<<<NE / 256, 256, 0, stream>>>(e_row, e_col, ea, dinv, row_ptr, rank, epack);

    // layer 1: x[NN x 128] @ W1 -> T; gather -> A (ReLU)
    mm64t<128><<<NN / 64, 256, 0, stream>>>(x, W1, T);
    gather64<true><<<NN / 4, 256, 0, stream>>>(T, b1, dinv, row_ptr, (const long long*)epack, A);
    // layers 2..5
    mm64t<64><<<NN / 64, 256, 0, stream>>>(A, W2, T);
    gather64<true><<<NN / 4, 256, 0, stream>>>(T, b2, dinv, row_ptr, (const long long*)epack, A);
    mm64t<64><<<NN / 64, 256, 0, stream>>>(A, W3, T);
    gather64<true><<<NN / 4, 256, 0, stream>>>(T, b3, dinv, row_ptr, (const long long*)epack, A);
    mm64t<64><<<NN / 64, 256, 0, stream>>>(A, W4, T);
    gather64<true><<<NN / 4, 256, 0, stream>>>(T, b4, dinv, row_ptr, (const long long*)epack, A);
    mm64t<64><<<NN / 64, 256, 0, stream>>>(A, W5, T);
    gather64<true><<<NN / 4, 256, 0, stream>>>(T, b5, dinv, row_ptr, (const long long*)epack, A);
    // layer 8
    mm2<<<NN / 4, 256, 0, stream>>>(A, W8, T8);
    gather2<<<NN / 4, 256, 0, stream>>>(T8, b8, dinv, row_ptr, epack, out);
}

// Round 6
// 393.990 us; speedup vs baseline: 1.2201x; 1.2201x over previous
//
#include <hip/hip_runtime.h>
#include <math.h>

#define NN 65536
#define NE 1048576
#define DEG_SCALE 33554432.0f  // 2^25

__device__ inline float4 f4fma(float s, float4 v, float4 a) {
    a.x = fmaf(s, v.x, a.x);
    a.y = fmaf(s, v.y, a.y);
    a.z = fmaf(s, v.z, a.z);
    a.w = fmaf(s, v.w, a.w);
    return a;
}

// ---------------- setup kernels ----------------

// one 64-bit atomic per edge: high32 = count, low32 = fixed-point(ew * 2^25).
// weighted degree < 64 -> low word < 2^31, never carries into count.
// atomic returns old value -> old count == this edge's rank within its target bin.
__global__ void __launch_bounds__(256) deg_count(const int* __restrict__ col,
                                                 const float* __restrict__ ew,
                                                 unsigned long long* __restrict__ cntdeg,
                                                 int* __restrict__ rank) {
    int e = blockIdx.x * 256 + threadIdx.x;
    if (e < NE) {
        int c = col[e];
        unsigned long long p = (1ull << 32) | (unsigned long long)__float2uint_rn(ew[e] * DEG_SCALE);
        unsigned long long old = atomicAdd(&cntdeg[c], p);
        rank[e] = (int)(old >> 32);
    }
}

// phase 1: per-block (256 nodes) exclusive scan of counts; emit block total + dinv.
__global__ void __launch_bounds__(256) scan1(const unsigned long long* __restrict__ cntdeg,
                                             int* __restrict__ row_ptr,
                                             int* __restrict__ blocksum,
                                             float* __restrict__ dinv) {
    __shared__ int ls[256];
    const int t = threadIdx.x;
    const int i = blockIdx.x * 256 + t;
    unsigned long long v = cntdeg[i];
    const int c = (int)(v >> 32);
    float deg = (float)(unsigned)(v & 0xffffffffull) * (1.0f / DEG_SCALE) + 1.0f;
    dinv[i] = 1.0f / sqrtf(deg);
    ls[t] = c;
    __syncthreads();
#pragma unroll
    for (int off = 1; off < 256; off <<= 1) {
        int u = (t >= off) ? ls[t - off] : 0;
        __syncthreads();
        ls[t] += u;
        __syncthreads();
    }
    row_ptr[i] = ls[t] - c;  // exclusive
    if (t == 255) blocksum[blockIdx.x] = ls[255];
}

// phase 2: single block scans the 256 block sums -> exclusive bases; writes total.
__global__ void __launch_bounds__(256) scan2(int* __restrict__ blocksum,
                                             int* __restrict__ blockbase,
                                             int* __restrict__ row_ptr) {
    __shared__ int ls[256];
    const int t = threadIdx.x;
    const int c = blocksum[t];
    ls[t] = c;
    __syncthreads();
#pragma unroll
    for (int off = 1; off < 256; off <<= 1) {
        int u = (t >= off) ? ls[t - off] : 0;
        __syncthreads();
        ls[t] += u;
        __syncthreads();
    }
    blockbase[t] = ls[t] - c;
    if (t == 255) row_ptr[NN] = ls[255];
}

// phase 3: broadcast-add block base.
__global__ void __launch_bounds__(256) scan3(int* __restrict__ row_ptr,
                                             const int* __restrict__ blockbase) {
    const int i = blockIdx.x * 256 + threadIdx.x;
    row_ptr[i] += blockbase[blockIdx.x];
}

// atomic-free CSR fill using precomputed rank.
__global__ void __launch_bounds__(256) fill_kernel(const int* __restrict__ row,
                                                   const int* __restrict__ col,
                                                   const float* __restrict__ ew,
                                                   const float* __restrict__ dinv,
                                                   const int* __restrict__ row_ptr,
                                                   const int* __restrict__ rank,
                                                   int2* __restrict__ epack) {
    int e = blockIdx.x * 256 + threadIdx.x;
    if (e < NE) {
        int c = col[e], r = row[e];
        int idx = row_ptr[c] + rank[e];
        int2 p;
        p.x = r;
        p.y = __float_as_int(dinv[r] * ew[e] * dinv[c]);
        epack[idx] = p;
    }
}

// ---------------- per-layer kernels ----------------

// C[NN x 64] = A[NN x K] @ W[K x 64]; 64-node x 64-col tile per block, 4x4 per thread.
template <int K>
__global__ void __launch_bounds__(256) mm64t(const float* __restrict__ A,
                                             const float* __restrict__ W,
                                             float* __restrict__ C) {
    __shared__ float As[64 * 68];
    __shared__ float Ws[64 * 64];
    const int tid = threadIdx.x;
    const int tx = tid & 15;
    const int ty = tid >> 4;
    const int node0 = blockIdx.x * 64;
    float4 acc[4];
#pragma unroll
    for (int m = 0; m < 4; ++m) acc[m] = make_float4(0.f, 0.f, 0.f, 0.f);

    for (int kc = 0; kc < K; kc += 64) {
#pragma unroll
        for (int p = 0; p < 4; ++p) {
            int idx = tid + p * 256;
            int r = idx >> 4, c4 = idx & 15;
            float4 v = *reinterpret_cast<const float4*>(A + (size_t)(node0 + r) * K + kc + c4 * 4);
            *reinterpret_cast<float4*>(&As[r * 68 + c4 * 4]) = v;
        }
#pragma unroll
        for (int p = 0; p < 4; ++p) {
            int idx = tid + p * 256;
            int r = idx >> 4, c4 = idx & 15;
            float4 v = *reinterpret_cast<const float4*>(W + (size_t)(kc + r) * 64 + c4 * 4);
            *reinterpret_cast<float4*>(&Ws[r * 64 + c4 * 4]) = v;
        }
        __syncthreads();
#pragma unroll 16
        for (int k = 0; k < 64; ++k) {
            float4 w = *reinterpret_cast<const float4*>(&Ws[k * 64 + tx * 4]);
            float a0 = As[(ty * 4 + 0) * 68 + k];
            float a1 = As[(ty * 4 + 1) * 68 + k];
            float a2 = As[(ty * 4 + 2) * 68 + k];
            float a3 = As[(ty * 4 + 3) * 68 + k];
            acc[0] = f4fma(a0, w, acc[0]);
            acc[1] = f4fma(a1, w, acc[1]);
            acc[2] = f4fma(a2, w, acc[2]);
            acc[3] = f4fma(a3, w, acc[3]);
        }
        __syncthreads();
    }
#pragma unroll
    for (int m = 0; m < 4; ++m)
        *reinterpret_cast<float4*>(C + (size_t)(node0 + ty * 4 + m) * 64 + tx * 4) = acc[m];
}

// out[n][:] = act( b + dinv[n]^2*T[n] + sum_e enorm[e]*T[esrc[e]] )
// wave per node; 4 edge-groups x 16 lanes (float4/lane), 4x unrolled -> 16 row loads in flight.
template <bool RELU>
__global__ void __launch_bounds__(256) gather64(const float* __restrict__ T,
                                                const float* __restrict__ bias,
                                                const float* __restrict__ dinv,
                                                const int* __restrict__ row_ptr,
                                                const int2* __restrict__ epack,
                                                float* __restrict__ out) {
    const int tid = threadIdx.x;
    const int lane = tid & 63;
    const int g = lane >> 4;   // edge group 0..3
    const int l = lane & 15;   // float4 index within row
    const int node = blockIdx.x * 4 + (tid >> 6);
    const float4* T4 = reinterpret_cast<const float4*>(T);

    const float dv = dinv[node];
    float4 acc = make_float4(0.f, 0.f, 0.f, 0.f);
    if (g == 0) {
        float4 b4 = reinterpret_cast<const float4*>(bias)[l];
        float4 ts = T4[(size_t)node * 16 + l];
        acc.x = b4.x + dv * dv * ts.x;
        acc.y = b4.y + dv * dv * ts.y;
        acc.z = b4.z + dv * dv * ts.z;
        acc.w = b4.w + dv * dv * ts.w;
    }
    const int s = row_ptr[node];
    const int e = row_ptr[node + 1];
    int i = s + g;
    for (; i + 12 < e; i += 16) {
        int2 p0 = epack[i];
        int2 p1 = epack[i + 4];
        int2 p2 = epack[i + 8];
        int2 p3 = epack[i + 12];
        float4 r0 = T4[(size_t)p0.x * 16 + l];
        float4 r1 = T4[(size_t)p1.x * 16 + l];
        float4 r2 = T4[(size_t)p2.x * 16 + l];
        float4 r3 = T4[(size_t)p3.x * 16 + l];
        acc = f4fma(__int_as_float(p0.y), r0, acc);
        acc = f4fma(__int_as_float(p1.y), r1, acc);
        acc = f4fma(__int_as_float(p2.y), r2, acc);
        acc = f4fma(__int_as_float(p3.y), r3, acc);
    }
    for (; i < e; i += 4) {
        int2 p0 = epack[i];
        acc = f4fma(__int_as_float(p0.y), T4[(size_t)p0.x * 16 + l], acc);
    }
    // reduce across the 4 edge groups (butterfly over lane bits 4,5)
    acc.x += __shfl_xor(acc.x, 16);
    acc.y += __shfl_xor(acc.y, 16);
    acc.z += __shfl_xor(acc.z, 16);
    acc.w += __shfl_xor(acc.w, 16);
    acc.x += __shfl_xor(acc.x, 32);
    acc.y += __shfl_xor(acc.y, 32);
    acc.z += __shfl_xor(acc.z, 32);
    acc.w += __shfl_xor(acc.w, 32);
    if (RELU) {
        acc.x = fmaxf(acc.x, 0.f);
        acc.y = fmaxf(acc.y, 0.f);
        acc.z = fmaxf(acc.z, 0.f);
        acc.w = fmaxf(acc.w, 0.f);
    }
    if (g == 0) reinterpret_cast<float4*>(out)[(size_t)node * 16 + l] = acc;
}

// T8[NN x 2] = A[NN x 64] @ W8[64 x 2]; wave per node, shuffle reduction.
__global__ void __launch_bounds__(256) mm2(const float* __restrict__ A,
                                           const float* __restrict__ W8,
                                           float* __restrict__ T8) {
    const int lane = threadIdx.x & 63;
    const int node = blockIdx.x * 4 + (threadIdx.x >> 6);
    const float a = A[(size_t)node * 64 + lane];
    float p0 = a * W8[lane * 2 + 0];
    float p1 = a * W8[lane * 2 + 1];
    for (int o = 32; o > 0; o >>= 1) {
        p0 += __shfl_xor(p0, o);
        p1 += __shfl_xor(p1, o);
    }
    if (lane == 0) {
        T8[node * 2 + 0] = p0;
        T8[node * 2 + 1] = p1;
    }
}

// wave per node; lane = (edge j 0..31) x (col c 0..1); 32 edges in flight.
__global__ void __launch_bounds__(256) gather2(const float* __restrict__ T8,
                                               const float* __restrict__ b8,
                                               const float* __restrict__ dinv,
                                               const int* __restrict__ row_ptr,
                                               const int2* __restrict__ epack,
                                               float* __restrict__ out) {
    const int lane = threadIdx.x & 63;
    const int c = lane & 1;
    const int j = lane >> 1;  // 0..31
    const int node = blockIdx.x * 4 + (threadIdx.x >> 6);
    const int s = row_ptr[node];
    const int e = row_ptr[node + 1];
    float acc = 0.f;
    for (int i = s + j; i < e; i += 32) {
        int2 p = epack[i];
        acc += __int_as_float(p.y) * T8[(size_t)p.x * 2 + c];
    }
    acc += __shfl_xor(acc, 2);
    acc += __shfl_xor(acc, 4);
    acc += __shfl_xor(acc, 8);
    acc += __shfl_xor(acc, 16);
    acc += __shfl_xor(acc, 32);
    if (j == 0) {
        const float dv = dinv[node];
        out[(size_t)node * 2 + c] = b8[c] + dv * dv * T8[(size_t)node * 2 + c] + acc;
    }
}

// ---------------- launcher ----------------

extern "C" void kernel_launch(void* const* d_in, const int* in_sizes, int n_in,
                              void* d_out, int out_size, void* d_ws, size_t ws_size,
                              hipStream_t stream) {
    const float* x  = (const float*)d_in[0];
    const int*   ei = (const int*)d_in[1];   // [2, NE]: [0:NE)=row(src), [NE:2NE)=col(dst)
    const float* ea = (const float*)d_in[2];
    const float* W1 = (const float*)d_in[3];
    const float* b1 = (const float*)d_in[4];
    const float* W2 = (const float*)d_in[5];
    const float* b2 = (const float*)d_in[6];
    const float* W3 = (const float*)d_in[7];
    const float* b3 = (const float*)d_in[8];
    const float* W4 = (const float*)d_in[9];
    const float* b4 = (const float*)d_in[10];
    const float* W5 = (const float*)d_in[11];
    const float* b5 = (const float*)d_in[12];
    const float* W8 = (const float*)d_in[13];
    const float* b8 = (const float*)d_in[14];
    float* out = (float*)d_out;

    // workspace layout (fp32/i32 words)
    float* T      = (float*)d_ws;                 // NN*64
    float* A      = T + (size_t)NN * 64;          // NN*64  (rank aliases A: rank is dead
    int*   rank   = (int*)A;                      //         before gather64 first writes A)
    int2*  epack  = (int2*)(A + (size_t)NN * 64); // NE int2
    unsigned long long* cntdeg = (unsigned long long*)(epack + NE);  // NN ull
    float* dinv   = (float*)(cntdeg + NN);        // NN
    int*   row_ptr= (int*)(dinv + NN);            // NN+1
    float* T8     = (float*)(row_ptr + NN + 1);   // NN*2
    int*   blocksum  = (int*)(T8 + (size_t)NN * 2);  // 256
    int*   blockbase = blocksum + 256;               // 256

    const int* e_row = ei;
    const int* e_col = ei + NE;

    (void)hipMemsetAsync(cntdeg, 0, (size_t)NN * 8, stream);  // cntdeg only

    deg_count<<<NE / 256, 256, 0, stream>>>(e_col, ea, cntdeg, rank);
    scan1<<<NN / 256, 256, 0, stream>>>(cntdeg, row_ptr, blocksum, dinv);
    scan2<<<1, 256, 0, stream>>>(blocksum, blockbase, row_ptr);
    scan3<<<NN / 256, 256, 0, stream>>>(row_ptr, blockbase);
    fill_kernel<<<NE / 256, 256, 0, stream>>>(e_row, e_col, ea, dinv, row_ptr, rank, epack);

    // layer 1: x[NN x 128] @ W1 -> T; gather -> A (ReLU)
    mm64t<128><<<NN / 64, 256, 0, stream>>>(x, W1, T);
    gather64<true><<<NN / 4, 256, 0, stream>>>(T, b1, dinv, row_ptr, epack, A);
    // layers 2..5
    mm64t<64><<<NN / 64, 256, 0, stream>>>(A, W2, T);
    gather64<true><<<NN / 4, 256, 0, stream>>>(T, b2, dinv, row_ptr, epack, A);
    mm64t<64><<<NN / 64, 256, 0, stream>>>(A, W3, T);
    gather64<true><<<NN / 4, 256, 0, stream>>>(T, b3, dinv, row_ptr, epack, A);
    mm64t<64><<<NN / 64, 256, 0, stream>>>(A, W4, T);
    gather64<true><<<NN / 4, 256, 0, stream>>>(T, b4, dinv, row_ptr, epack, A);
    mm64t<64><<<NN / 64, 256, 0, stream>>>(A, W5, T);
    gather64<true><<<NN / 4, 256, 0, stream>>>(T, b5, dinv, row_ptr, epack, A);
    // layer 8
    mm2<<<NN / 4, 256, 0, stream>>>(A, W8, T8);
    gather2<<<NN / 4, 256, 0, stream>>>(T8, b8, dinv, row_ptr, epack, out);
}